// Round 3
// baseline (588.086 us; speedup 1.0000x reference)
//
#include <hip/hip_runtime.h>
#include <hip/hip_bf16.h>

typedef __hip_bfloat16 bf16;

#define B_ 4
#define R_ 512
#define C_ 512
#define E_ 256
#define H_ 16
#define D_ 16

__device__ __forceinline__ float tofloat(float x) { return x; }
__device__ __forceinline__ float tofloat(bf16 x) { return __bfloat162float(x); }

// ---------------- Register-blocked GEMM: C[M,N] = A[M,K] @ Bw[K,N] (+bias)(+res)(relu) ----------------
// BM=64, BN=64, BK=16, 256 threads, 4x4 micro-tile per thread.
// RES: 0 = none, 1 = residual (WT*), 2 = f32 residual
template <typename AT, typename WT, int RES, bool RELU, bool BIAS>
__global__ __launch_bounds__(256) void gemm_kernel(
    const AT* __restrict__ A, const WT* __restrict__ Bw,
    const WT* __restrict__ bias, const void* __restrict__ Res,
    float* __restrict__ Cout, int M, int N, int K)
{
    __shared__ float As[16][65];
    __shared__ float Bs[16][64];
    const int tid = threadIdx.x;
    const int m0 = blockIdx.y * 64;
    const int n0 = blockIdx.x * 64;
    const int tm = tid >> 4;
    const int tn = tid & 15;
    const int la_m = tid >> 2;
    const int la_k = (tid & 3) << 2;
    const int lb_k = tid >> 4;
    const int lb_n = (tid & 15) << 2;

    float acc[4][4] = {};

    for (int k0 = 0; k0 < K; k0 += 16) {
        const AT* ap = A + (size_t)(m0 + la_m) * K + (k0 + la_k);
        As[la_k + 0][la_m] = tofloat(ap[0]);
        As[la_k + 1][la_m] = tofloat(ap[1]);
        As[la_k + 2][la_m] = tofloat(ap[2]);
        As[la_k + 3][la_m] = tofloat(ap[3]);
        const WT* bp = Bw + (size_t)(k0 + lb_k) * N + (n0 + lb_n);
        Bs[lb_k][lb_n + 0] = tofloat(bp[0]);
        Bs[lb_k][lb_n + 1] = tofloat(bp[1]);
        Bs[lb_k][lb_n + 2] = tofloat(bp[2]);
        Bs[lb_k][lb_n + 3] = tofloat(bp[3]);
        __syncthreads();
#pragma unroll
        for (int kk = 0; kk < 16; kk++) {
            float av[4], bv[4];
#pragma unroll
            for (int i = 0; i < 4; i++) av[i] = As[kk][tm * 4 + i];
#pragma unroll
            for (int j = 0; j < 4; j++) bv[j] = Bs[kk][tn * 4 + j];
#pragma unroll
            for (int i = 0; i < 4; i++)
#pragma unroll
                for (int j = 0; j < 4; j++)
                    acc[i][j] = fmaf(av[i], bv[j], acc[i][j]);
        }
        __syncthreads();
    }

#pragma unroll
    for (int i = 0; i < 4; i++) {
        const int row = m0 + tm * 4 + i;
#pragma unroll
        for (int j = 0; j < 4; j++) {
            const int col = n0 + tn * 4 + j;
            float v = acc[i][j];
            if (BIAS) v += tofloat(bias[col]);
            if (RES == 1) v += tofloat(((const WT*)Res)[(size_t)row * N + col]);
            if (RES == 2) v += ((const float*)Res)[(size_t)row * N + col];
            if (RELU) v = fmaxf(v, 0.f);
            Cout[(size_t)row * N + col] = v;
        }
    }
}

// ---------------- Fused attention: one wave per (b,h,r); 8 columns per lane ----------------
__global__ __launch_bounds__(256) void attn_kernel(
    const float* __restrict__ q, const float* __restrict__ k, const float* __restrict__ v,
    const float* __restrict__ cost, const float* __restrict__ m1w, const float* __restrict__ m1b,
    const float* __restrict__ m2w, const float* __restrict__ m2b,
    float* __restrict__ outp)
{
    const int wid = blockIdx.x * 4 + (threadIdx.x >> 6);
    const int lane = threadIdx.x & 63;
    const int b = wid >> 13;        // / (H*R)
    const int h = (wid >> 9) & 15;  // / R % H
    const int r = wid & 511;        // % R

    const float4* qrow = (const float4*)(q + ((size_t)(b * R_ + r) * 256 + h * 16));
    const float4 q0 = qrow[0], q1 = qrow[1], q2 = qrow[2], q3 = qrow[3];

    float w1a[16], w1b[16], b1v[16], w2v[16];
#pragma unroll
    for (int m = 0; m < 16; m++) {
        w1a[m] = m1w[h * 32 + m];        // mix1_w[h][0][m] (dot)
        w1b[m] = m1w[h * 32 + 16 + m];   // mix1_w[h][1][m] (cost)
        b1v[m] = m1b[h * 16 + m];
        w2v[m] = m2w[h * 16 + m];
    }
    const float b2v = m2b[h];

    float mixed[8];
#pragma unroll
    for (int j = 0; j < 8; j++) {
        const int c = j * 64 + lane;
        const float4* kr = (const float4*)(k + ((size_t)(b * C_ + c) * 256 + h * 16));
        const float4 k0 = kr[0], k1 = kr[1], k2 = kr[2], k3 = kr[3];
        float dot = q0.x * k0.x + q0.y * k0.y + q0.z * k0.z + q0.w * k0.w
                  + q1.x * k1.x + q1.y * k1.y + q1.z * k1.z + q1.w * k1.w
                  + q2.x * k2.x + q2.y * k2.y + q2.z * k2.z + q2.w * k2.w
                  + q3.x * k3.x + q3.y * k3.y + q3.z * k3.z + q3.w * k3.w;
        dot *= 0.25f;  // 1/sqrt(D=16)
        const float cst = cost[(size_t)(b * R_ + r) * C_ + c];
        float acc = b2v;
#pragma unroll
        for (int m = 0; m < 16; m++) {
            float t = fmaf(dot, w1a[m], fmaf(cst, w1b[m], b1v[m]));
            t = fmaxf(t, 0.f);
            acc = fmaf(t, w2v[m], acc);
        }
        mixed[j] = acc;
    }

    // softmax over the 512 columns (8 per lane x 64 lanes)
    float mx = mixed[0];
#pragma unroll
    for (int j = 1; j < 8; j++) mx = fmaxf(mx, mixed[j]);
#pragma unroll
    for (int off = 32; off; off >>= 1) mx = fmaxf(mx, __shfl_xor(mx, off, 64));
    float s = 0.f;
#pragma unroll
    for (int j = 0; j < 8; j++) { mixed[j] = __expf(mixed[j] - mx); s += mixed[j]; }
#pragma unroll
    for (int off = 32; off; off >>= 1) s += __shfl_xor(s, off, 64);
    const float inv = 1.f / s;

    float oa[16] = {};
#pragma unroll
    for (int j = 0; j < 8; j++) {
        const float w = mixed[j] * inv;
        const int c = j * 64 + lane;
        const float4* vr = (const float4*)(v + ((size_t)(b * C_ + c) * 256 + h * 16));
        const float4 v0 = vr[0], v1 = vr[1], v2 = vr[2], v3 = vr[3];
        oa[0] += w * v0.x; oa[1] += w * v0.y; oa[2]  += w * v0.z; oa[3]  += w * v0.w;
        oa[4] += w * v1.x; oa[5] += w * v1.y; oa[6]  += w * v1.z; oa[7]  += w * v1.w;
        oa[8] += w * v2.x; oa[9] += w * v2.y; oa[10] += w * v2.z; oa[11] += w * v2.w;
        oa[12] += w * v3.x; oa[13] += w * v3.y; oa[14] += w * v3.z; oa[15] += w * v3.w;
    }
#pragma unroll
    for (int off = 32; off; off >>= 1)
#pragma unroll
        for (int d = 0; d < 16; d++) oa[d] += __shfl_xor(oa[d], off, 64);

    if (lane == 0) {
        float4* op = (float4*)(outp + ((size_t)(b * R_ + r) * 256 + h * 16));
        op[0] = make_float4(oa[0], oa[1], oa[2], oa[3]);
        op[1] = make_float4(oa[4], oa[5], oa[6], oa[7]);
        op[2] = make_float4(oa[8], oa[9], oa[10], oa[11]);
        op[3] = make_float4(oa[12], oa[13], oa[14], oa[15]);
    }
}

// ---------------- InstanceNorm stats: one wave per (b,e), reduce over R=512 ----------------
__global__ __launch_bounds__(64) void in_stats_kernel(
    const float* __restrict__ xin, float* __restrict__ mean, float* __restrict__ rstd)
{
    const int be = blockIdx.x;  // b*256 + e
    const int b = be >> 8;
    const int e = be & 255;
    const int lane = threadIdx.x;
    const float* base = xin + (size_t)b * R_ * E_ + e;
    float s = 0.f, ss = 0.f;
#pragma unroll
    for (int i = 0; i < 8; i++) {
        const float v = base[(size_t)(lane + 64 * i) * E_];
        s += v; ss += v * v;
    }
#pragma unroll
    for (int off = 32; off; off >>= 1) {
        s += __shfl_xor(s, off, 64);
        ss += __shfl_xor(ss, off, 64);
    }
    if (lane == 0) {
        const float m = s * (1.f / 512.f);
        float var = ss * (1.f / 512.f) - m * m;
        var = fmaxf(var, 0.f);
        mean[be] = m;
        rstd[be] = rsqrtf(var + 1e-5f);
    }
}

// ---------------- Apply instance norm (+affine) ----------------
__global__ __launch_bounds__(256) void apply_in_kernel(
    const float* __restrict__ xin, const float* __restrict__ mean, const float* __restrict__ rstd,
    const float* __restrict__ g, const float* __restrict__ be, float* __restrict__ outp)
{
    const int idx = blockIdx.x * 256 + threadIdx.x;  // < B*R*E = 524288
    const int e = idx & 255;
    const int b = idx >> 17;  // R*E = 2^17
    const int sidx = (b << 8) | e;
    outp[idx] = (xin[idx] - mean[sidx]) * rstd[sidx] * g[e] + be[e];
}

extern "C" void kernel_launch(void* const* d_in, const int* in_sizes, int n_in,
                              void* d_out, int out_size, void* d_ws, size_t ws_size,
                              hipStream_t stream)
{
    (void)in_sizes; (void)n_in; (void)out_size; (void)ws_size;
    const float* row_emb = (const float*)d_in[0];
    const float* col_emb = (const float*)d_in[1];
    const float* cost    = (const float*)d_in[2];
    const float* Wq  = (const float*)d_in[3];
    const float* Wk  = (const float*)d_in[4];
    const float* Wv  = (const float*)d_in[5];
    const float* m1w = (const float*)d_in[6];
    const float* m1b = (const float*)d_in[7];
    const float* m2w = (const float*)d_in[8];
    const float* m2b = (const float*)d_in[9];
    const float* Wc  = (const float*)d_in[10];
    const float* bc  = (const float*)d_in[11];
    const float* W1  = (const float*)d_in[12];
    const float* b1  = (const float*)d_in[13];
    const float* W2  = (const float*)d_in[14];
    const float* b2  = (const float*)d_in[15];
    const float* g1  = (const float*)d_in[16];
    const float* be1 = (const float*)d_in[17];
    const float* g2  = (const float*)d_in[18];
    const float* be2 = (const float*)d_in[19];
    float* out = (float*)d_out;

    // Workspace: 4 x SZ fp32 buffers + 4096 stats floats = 8,404,992 B
    float* ws = (float*)d_ws;
    const size_t SZ = 2048u * 256u;  // 524288 (one [B*L, 256] fp32 tensor)
    float* s0 = ws;
    float* s1 = ws + SZ;
    float* s2 = ws + 2 * SZ;
    float* s3 = ws + 3 * SZ;
    float* mean1 = ws + 4 * SZ;
    float* rstd1 = mean1 + 1024;
    float* mean2 = rstd1 + 1024;
    float* rstd2 = mean2 + 1024;

    const dim3 blk(256);
    // Phase 1: QKV projections (q->s0, k->s1, v->s2)
    gemm_kernel<float, float, 0, false, false><<<dim3(4, 32), blk, 0, stream>>>(row_emb, Wq, nullptr, nullptr, s0, 2048, 256, 256);
    gemm_kernel<float, float, 0, false, false><<<dim3(4, 32), blk, 0, stream>>>(col_emb, Wk, nullptr, nullptr, s1, 2048, 256, 256);
    gemm_kernel<float, float, 0, false, false><<<dim3(4, 32), blk, 0, stream>>>(col_emb, Wv, nullptr, nullptr, s2, 2048, 256, 256);

    // Phase 2: fused score-MLP + softmax + PV -> attn (s3)
    attn_kernel<<<dim3(8192), blk, 0, stream>>>(s0, s1, s2, cost, m1w, m1b, m2w, m2b, s3);

    // Phase 3: multi_head_combine + residual: y = attn @ Wc + bc + row_emb -> s0
    gemm_kernel<float, float, 1, false, true><<<dim3(4, 32), blk, 0, stream>>>(s3, Wc, bc, row_emb, s0, 2048, 256, 256);

    // Phase 4: InstanceNorm1(y) -> x (s1)
    in_stats_kernel<<<dim3(1024), dim3(64), 0, stream>>>(s0, mean1, rstd1);
    apply_in_kernel<<<dim3(2048), blk, 0, stream>>>(s0, mean1, rstd1, g1, be1, s1);

    // Phase 5: FFN. hmid = relu(x@W1+b1) -> s2..s3 (2 SZ); t = hmid@W2+b2+x -> s0
    gemm_kernel<float, float, 0, true, true><<<dim3(8, 32), blk, 0, stream>>>(s1, W1, b1, nullptr, s2, 2048, 512, 256);
    gemm_kernel<float, float, 2, false, true><<<dim3(4, 32), blk, 0, stream>>>(s2, W2, b2, s1, s0, 2048, 256, 512);

    // Phase 6: InstanceNorm2(t) -> d_out (fp32)
    in_stats_kernel<<<dim3(1024), dim3(64), 0, stream>>>(s0, mean2, rstd2);
    apply_in_kernel<<<dim3(2048), blk, 0, stream>>>(s0, mean2, rstd2, g2, be2, out);
}

// Round 4
// 256.503 us; speedup vs baseline: 2.2927x; 2.2927x over previous
//
#include <hip/hip_runtime.h>
#include <hip/hip_bf16.h>

#define B_ 4
#define R_ 512
#define C_ 512
#define E_ 256
#define H_ 16
#define D_ 16

// ---------------- Register-blocked GEMM body: C[M,N] = A[M,K] @ Bw[K,N] ----------------
// BM x 64 tile, BK=16, 256 threads, (BM/16) x 4 micro-tile per thread.
template <int BM, bool RES, bool RELU, bool BIAS>
__device__ __forceinline__ void gemm_body(
    const float* __restrict__ A, const float* __restrict__ Bw,
    const float* __restrict__ bias, const float* __restrict__ Res,
    float* __restrict__ Cout, int M, int N, int K, int bx, int by)
{
    constexpr int RM = BM / 16;       // rows per thread
    constexpr int TPR = 16 / RM;      // threads per row-group in staging
    __shared__ float As[16][BM + 1];
    __shared__ float Bs[16][64];
    const int tid = threadIdx.x;
    const int m0 = by * BM;
    const int n0 = bx * 64;
    const int tm = tid >> 4;          // 0..15
    const int tn = tid & 15;          // 0..15
    const int la_m = tid / TPR;       // 0..BM-1
    const int la_k = (tid % TPR) * RM;
    const int lb_k = tid >> 4;        // 0..15
    const int lb_n = (tid & 15) << 2; // 0..60

    float acc[RM][4] = {};

    for (int k0 = 0; k0 < K; k0 += 16) {
        const float* ap = A + (size_t)(m0 + la_m) * K + (k0 + la_k);
#pragma unroll
        for (int i = 0; i < RM; i++) As[la_k + i][la_m] = ap[i];
        const float* bp = Bw + (size_t)(k0 + lb_k) * N + (n0 + lb_n);
        const float4 bq = *(const float4*)bp;
        Bs[lb_k][lb_n + 0] = bq.x;
        Bs[lb_k][lb_n + 1] = bq.y;
        Bs[lb_k][lb_n + 2] = bq.z;
        Bs[lb_k][lb_n + 3] = bq.w;
        __syncthreads();
#pragma unroll
        for (int kk = 0; kk < 16; kk++) {
            float av[RM], bv[4];
#pragma unroll
            for (int i = 0; i < RM; i++) av[i] = As[kk][tm * RM + i];
#pragma unroll
            for (int j = 0; j < 4; j++) bv[j] = Bs[kk][tn * 4 + j];
#pragma unroll
            for (int i = 0; i < RM; i++)
#pragma unroll
                for (int j = 0; j < 4; j++)
                    acc[i][j] = fmaf(av[i], bv[j], acc[i][j]);
        }
        __syncthreads();
    }

#pragma unroll
    for (int i = 0; i < RM; i++) {
        const int row = m0 + tm * RM + i;
#pragma unroll
        for (int j = 0; j < 4; j++) {
            const int col = n0 + tn * 4 + j;
            float vv = acc[i][j];
            if (BIAS) vv += bias[col];
            if (RES) vv += Res[(size_t)row * N + col];
            if (RELU) vv = fmaxf(vv, 0.f);
            Cout[(size_t)row * N + col] = vv;
        }
    }
}

template <int BM, bool RES, bool RELU, bool BIAS>
__global__ __launch_bounds__(256) void gemm_kernel(
    const float* __restrict__ A, const float* __restrict__ Bw,
    const float* __restrict__ bias, const float* __restrict__ Res,
    float* __restrict__ Cout, int M, int N, int K)
{
    gemm_body<BM, RES, RELU, BIAS>(A, Bw, bias, Res, Cout, M, N, K, blockIdx.x, blockIdx.y);
}

// Fused QKV: z selects (A, W, out); one dispatch, grid (4,32,3) = 384 WGs.
__global__ __launch_bounds__(256) void qkv_kernel(
    const float* __restrict__ rowE, const float* __restrict__ colE,
    const float* __restrict__ Wq, const float* __restrict__ Wk, const float* __restrict__ Wv,
    float* __restrict__ qo, float* __restrict__ ko, float* __restrict__ vo)
{
    const int z = blockIdx.z;
    const float* A = (z == 0) ? rowE : colE;
    const float* W = (z == 0) ? Wq : (z == 1) ? Wk : Wv;
    float* O = (z == 0) ? qo : (z == 1) ? ko : vo;
    gemm_body<64, false, false, false>(A, W, nullptr, nullptr, O, 2048, 256, 256,
                                       blockIdx.x, blockIdx.y);
}

// ---------------- Attention: lane = row, iterate columns; k/v staged in LDS ----------------
// Grid: (rtile=8, h=16, b=4), 256 threads. Wave w handles c-chunk [w*128, w*128+128)
// for 64 rows (lane=row). Per-lane online softmax; 4-way c-chunk merge via LDS.
__global__ __launch_bounds__(256) void attn_kernel(
    const float* __restrict__ q, const float* __restrict__ k, const float* __restrict__ v,
    const float* __restrict__ cost, const float* __restrict__ m1w, const float* __restrict__ m1b,
    const float* __restrict__ m2w, const float* __restrict__ m2b,
    float* __restrict__ outp)
{
    __shared__ float smem[16384];  // [0,8192): k_lds[512][16]; [8192,16384): v_lds[512][16]
                                   // merge scratch aliases [0,4608) after barrier
    const int rt = blockIdx.x;
    const int h  = blockIdx.y;
    const int b  = blockIdx.z;
    const int tid = threadIdx.x;
    const int wid = tid >> 6;
    const int lane = tid & 63;

    // Stage k,v [512][16] for this (b,h): coalesced float4 loads.
    {
        const size_t base = ((size_t)b * C_) * 256 + h * 16;
        for (int i = tid; i < 2048; i += 256) {
            const int c = i >> 2, dp = (i & 3) << 2;
            const float4 kk = *(const float4*)(k + base + (size_t)c * 256 + dp);
            const float4 vv = *(const float4*)(v + base + (size_t)c * 256 + dp);
            *(float4*)(&smem[c * 16 + dp]) = kk;
            *(float4*)(&smem[8192 + c * 16 + dp]) = vv;
        }
    }

    // Per-head MLP weights: wave-uniform addresses -> scalar loads (SGPRs).
    float w1a[16], w1b[16], b1v[16], w2v[16];
#pragma unroll
    for (int m = 0; m < 16; m++) {
        w1a[m] = m1w[h * 32 + m];
        w1b[m] = m1w[h * 32 + 16 + m];
        b1v[m] = m1b[h * 16 + m];
        w2v[m] = m2w[h * 16 + m];
    }
    const float b2v = m2b[h];

    // This lane's q row (pre-scaled by 1/sqrt(D)=0.25).
    const int r = rt * 64 + lane;
    float qv[16];
    {
        const float4* qp = (const float4*)(q + ((size_t)(b * R_ + r) * 256 + h * 16));
#pragma unroll
        for (int i = 0; i < 4; i++) {
            const float4 t = qp[i];
            qv[i * 4 + 0] = t.x * 0.25f; qv[i * 4 + 1] = t.y * 0.25f;
            qv[i * 4 + 2] = t.z * 0.25f; qv[i * 4 + 3] = t.w * 0.25f;
        }
    }

    __syncthreads();

    const int c0 = wid * 128;
    const float* crow = cost + ((size_t)(b * R_ + r) * C_) + c0;
    float mrun = -1e30f, lrun = 0.f;
    float o[16] = {};

    for (int cc = 0; cc < 128; cc += 4) {
        const float4 cst4 = *(const float4*)(crow + cc);
#pragma unroll
        for (int u = 0; u < 4; u++) {
            const int c = c0 + cc + u;
            // k broadcast from LDS (all lanes same address)
            const float4* kr = (const float4*)(&smem[c * 16]);
            const float4 k0 = kr[0], k1 = kr[1], k2 = kr[2], k3 = kr[3];
            float d0 = fmaf(qv[0], k0.x, fmaf(qv[1], k0.y, fmaf(qv[2], k0.z, qv[3] * k0.w)));
            float d1 = fmaf(qv[4], k1.x, fmaf(qv[5], k1.y, fmaf(qv[6], k1.z, qv[7] * k1.w)));
            float d2 = fmaf(qv[8], k2.x, fmaf(qv[9], k2.y, fmaf(qv[10], k2.z, qv[11] * k2.w)));
            float d3 = fmaf(qv[12], k3.x, fmaf(qv[13], k3.y, fmaf(qv[14], k3.z, qv[15] * k3.w)));
            const float dot = (d0 + d1) + (d2 + d3);
            const float cst = (u == 0) ? cst4.x : (u == 1) ? cst4.y : (u == 2) ? cst4.z : cst4.w;
            // score MLP: 2 -> 16 -> 1
            float acc = b2v;
#pragma unroll
            for (int m = 0; m < 16; m++) {
                float t = fmaf(dot, w1a[m], fmaf(cst, w1b[m], b1v[m]));
                t = fmaxf(t, 0.f);
                acc = fmaf(t, w2v[m], acc);
            }
            // online softmax (rescale only when some lane's max moves)
            const float mnew = fmaxf(mrun, acc);
            if (__any(mnew > mrun)) {
                const float alpha = __expf(mrun - mnew);
                lrun *= alpha;
#pragma unroll
                for (int d = 0; d < 16; d++) o[d] *= alpha;
                mrun = mnew;
            }
            const float p = __expf(acc - mrun);
            lrun += p;
            const float4* vr = (const float4*)(&smem[8192 + c * 16]);
            const float4 v0 = vr[0], v1 = vr[1], v2 = vr[2], v3 = vr[3];
            o[0]  = fmaf(p, v0.x, o[0]);  o[1]  = fmaf(p, v0.y, o[1]);
            o[2]  = fmaf(p, v0.z, o[2]);  o[3]  = fmaf(p, v0.w, o[3]);
            o[4]  = fmaf(p, v1.x, o[4]);  o[5]  = fmaf(p, v1.y, o[5]);
            o[6]  = fmaf(p, v1.z, o[6]);  o[7]  = fmaf(p, v1.w, o[7]);
            o[8]  = fmaf(p, v2.x, o[8]);  o[9]  = fmaf(p, v2.y, o[9]);
            o[10] = fmaf(p, v2.z, o[10]); o[11] = fmaf(p, v2.w, o[11]);
            o[12] = fmaf(p, v3.x, o[12]); o[13] = fmaf(p, v3.y, o[13]);
            o[14] = fmaf(p, v3.z, o[14]); o[15] = fmaf(p, v3.w, o[15]);
        }
    }

    // Merge the 4 c-chunk partials (alias scratch over dead k_lds region).
    __syncthreads();
    smem[wid * 64 + lane] = mrun;
    smem[256 + wid * 64 + lane] = lrun;
    {
        float* po = &smem[512 + (wid * 64 + lane) * 16];
#pragma unroll
        for (int d = 0; d < 16; d++) po[d] = o[d];
    }
    __syncthreads();

    if (tid < 64) {
        const int rr = tid;
        float mm = smem[rr];
#pragma unroll
        for (int w = 1; w < 4; w++) mm = fmaxf(mm, smem[w * 64 + rr]);
        float ll = 0.f, oo[16] = {};
#pragma unroll
        for (int w = 0; w < 4; w++) {
            const float a = __expf(smem[w * 64 + rr] - mm);
            ll = fmaf(smem[256 + w * 64 + rr], a, ll);
            const float* po = &smem[512 + (w * 64 + rr) * 16];
#pragma unroll
            for (int d = 0; d < 16; d++) oo[d] = fmaf(po[d], a, oo[d]);
        }
        const float inv = 1.f / ll;
        float4* op = (float4*)(outp + ((size_t)(b * R_ + rt * 64 + rr) * 256 + h * 16));
        op[0] = make_float4(oo[0] * inv, oo[1] * inv, oo[2] * inv, oo[3] * inv);
        op[1] = make_float4(oo[4] * inv, oo[5] * inv, oo[6] * inv, oo[7] * inv);
        op[2] = make_float4(oo[8] * inv, oo[9] * inv, oo[10] * inv, oo[11] * inv);
        op[3] = make_float4(oo[12] * inv, oo[13] * inv, oo[14] * inv, oo[15] * inv);
    }
}

// ---------------- InstanceNorm stats: one wave per (b,e), reduce over R=512 ----------------
__global__ __launch_bounds__(64) void in_stats_kernel(
    const float* __restrict__ xin, float* __restrict__ mean, float* __restrict__ rstd)
{
    const int be = blockIdx.x;
    const int b = be >> 8;
    const int e = be & 255;
    const int lane = threadIdx.x;
    const float* base = xin + (size_t)b * R_ * E_ + e;
    float s = 0.f, ss = 0.f;
#pragma unroll
    for (int i = 0; i < 8; i++) {
        const float v = base[(size_t)(lane + 64 * i) * E_];
        s += v; ss += v * v;
    }
#pragma unroll
    for (int off = 32; off; off >>= 1) {
        s += __shfl_xor(s, off, 64);
        ss += __shfl_xor(ss, off, 64);
    }
    if (lane == 0) {
        const float m = s * (1.f / 512.f);
        float var = ss * (1.f / 512.f) - m * m;
        var = fmaxf(var, 0.f);
        mean[be] = m;
        rstd[be] = rsqrtf(var + 1e-5f);
    }
}

// ---------------- Apply instance norm (+affine) ----------------
__global__ __launch_bounds__(256) void apply_in_kernel(
    const float* __restrict__ xin, const float* __restrict__ mean, const float* __restrict__ rstd,
    const float* __restrict__ g, const float* __restrict__ be, float* __restrict__ outp)
{
    const int idx = blockIdx.x * 256 + threadIdx.x;
    const int e = idx & 255;
    const int b = idx >> 17;
    const int sidx = (b << 8) | e;
    outp[idx] = (xin[idx] - mean[sidx]) * rstd[sidx] * g[e] + be[e];
}

extern "C" void kernel_launch(void* const* d_in, const int* in_sizes, int n_in,
                              void* d_out, int out_size, void* d_ws, size_t ws_size,
                              hipStream_t stream)
{
    (void)in_sizes; (void)n_in; (void)out_size; (void)ws_size;
    const float* row_emb = (const float*)d_in[0];
    const float* col_emb = (const float*)d_in[1];
    const float* cost    = (const float*)d_in[2];
    const float* Wq  = (const float*)d_in[3];
    const float* Wk  = (const float*)d_in[4];
    const float* Wv  = (const float*)d_in[5];
    const float* m1w = (const float*)d_in[6];
    const float* m1b = (const float*)d_in[7];
    const float* m2w = (const float*)d_in[8];
    const float* m2b = (const float*)d_in[9];
    const float* Wc  = (const float*)d_in[10];
    const float* bc  = (const float*)d_in[11];
    const float* W1  = (const float*)d_in[12];
    const float* b1  = (const float*)d_in[13];
    const float* W2  = (const float*)d_in[14];
    const float* b2  = (const float*)d_in[15];
    const float* g1  = (const float*)d_in[16];
    const float* be1 = (const float*)d_in[17];
    const float* g2  = (const float*)d_in[18];
    const float* be2 = (const float*)d_in[19];
    float* out = (float*)d_out;

    float* ws = (float*)d_ws;
    const size_t SZ = 2048u * 256u;
    float* s0 = ws;
    float* s1 = ws + SZ;
    float* s2 = ws + 2 * SZ;
    float* s3 = ws + 3 * SZ;
    float* mean1 = ws + 4 * SZ;
    float* rstd1 = mean1 + 1024;
    float* mean2 = rstd1 + 1024;
    float* rstd2 = mean2 + 1024;

    const dim3 blk(256);

    // QKV fused: q->s0, k->s1, v->s2 (384 WGs)
    qkv_kernel<<<dim3(4, 32, 3), blk, 0, stream>>>(row_emb, col_emb, Wq, Wk, Wv, s0, s1, s2);

    // Attention (lane=row, LDS-staged k/v): -> s3 (512 WGs, 2/CU by LDS)
    attn_kernel<<<dim3(8, 16, 4), blk, 0, stream>>>(s0, s1, s2, cost, m1w, m1b, m2w, m2b, s3);

    // y = attn @ Wc + bc + row_emb -> s0 (BM=32: 256 WGs)
    gemm_kernel<32, true, false, true><<<dim3(4, 64), blk, 0, stream>>>(s3, Wc, bc, row_emb, s0, 2048, 256, 256);

    // InstanceNorm1 -> x (s1)
    in_stats_kernel<<<dim3(1024), dim3(64), 0, stream>>>(s0, mean1, rstd1);
    apply_in_kernel<<<dim3(2048), blk, 0, stream>>>(s0, mean1, rstd1, g1, be1, s1);

    // FFN: hmid = relu(x@W1+b1) -> s2 (512 WGs); t = hmid@W2+b2+x -> s0 (256 WGs)
    gemm_kernel<64, false, true, true><<<dim3(8, 32), blk, 0, stream>>>(s1, W1, b1, nullptr, s2, 2048, 512, 256);
    gemm_kernel<32, true, false, true><<<dim3(4, 64), blk, 0, stream>>>(s2, W2, b2, s1, s0, 2048, 256, 512);

    // InstanceNorm2 -> out
    in_stats_kernel<<<dim3(1024), dim3(64), 0, stream>>>(s0, mean2, rstd2);
    apply_in_kernel<<<dim3(2048), blk, 0, stream>>>(s0, mean2, rstd2, g2, be2, out);
}

// Round 5
// 194.004 us; speedup vs baseline: 3.0313x; 1.3222x over previous
//
#include <hip/hip_runtime.h>
#include <hip/hip_bf16.h>

typedef __hip_bfloat16 bf16;
typedef __hip_bfloat162 bf162;
typedef __attribute__((ext_vector_type(8))) short short8;
typedef __attribute__((ext_vector_type(4))) float f32x4;

#define B_ 4
#define R_ 512
#define C_ 512
#define E_ 256
#define H_ 16
#define D_ 16

// ================= Weight transpose+convert: W fp32 [K][N] -> WT bf16 [N][K] =================
// grid (128, 6); 32x32 tiles, 256 threads.
__global__ __launch_bounds__(256) void transpose_cvt_kernel(
    const float* __restrict__ Wq, const float* __restrict__ Wk, const float* __restrict__ Wv,
    const float* __restrict__ Wc, const float* __restrict__ W1, const float* __restrict__ W2,
    bf16* __restrict__ WqT, bf16* __restrict__ WkT, bf16* __restrict__ WvT,
    bf16* __restrict__ WcT, bf16* __restrict__ W1T, bf16* __restrict__ W2T)
{
    __shared__ bf16 tile[32][33];
    const int wsel = blockIdx.y;
    const float* src; bf16* dst; int K, N;
    switch (wsel) {
        case 0: src = Wq; dst = WqT; K = 256; N = 256; break;
        case 1: src = Wk; dst = WkT; K = 256; N = 256; break;
        case 2: src = Wv; dst = WvT; K = 256; N = 256; break;
        case 3: src = Wc; dst = WcT; K = 256; N = 256; break;
        case 4: src = W1; dst = W1T; K = 256; N = 512; break;
        default: src = W2; dst = W2T; K = 512; N = 256; break;
    }
    const int ntiles = (K >> 5) * (N >> 5);
    const int tx = blockIdx.x;
    if (tx >= ntiles) return;
    const int ncnt = N >> 5;
    const int tk = tx / ncnt, tn = tx % ncnt;
    const int c = threadIdx.x & 31, r = threadIdx.x >> 5;  // r in 0..7
#pragma unroll
    for (int i = 0; i < 4; i++) {
        const int kk = tk * 32 + r + i * 8;
        tile[r + i * 8][c] = __float2bfloat16(src[(size_t)kk * N + tn * 32 + c]);
    }
    __syncthreads();
#pragma unroll
    for (int i = 0; i < 4; i++) {
        const int nn = tn * 32 + r + i * 8;
        dst[(size_t)nn * K + tk * 32 + c] = tile[c][r + i * 8];
    }
}

// ================= MFMA GEMM: C[M,N] = A[M,K] @ B[K,N], BT given as [N][K] bf16 =================
// Tile BM x 64, BK=64, 256 threads (4 waves 2x2). Wave computes (BM/2) x 32.
// AT: float (cvt on stage) or bf16. RES: 0 none, 1 fp32 ptr, 2 bf16 ptr. Out bf16.
template <typename AT, int BM, bool BIAS, int RES, bool RELU>
__device__ __forceinline__ void mfma_gemm_body(
    const AT* __restrict__ A, const bf16* __restrict__ BT,
    const float* __restrict__ bias, const void* __restrict__ Res,
    bf16* __restrict__ Cout, int M, int N, int K, int bx, int by)
{
    constexpr int MT = BM / 32;              // m-tiles (16-row) per wave
    __shared__ bf16 As[BM * 80];             // [BM][64] pad to 80 (160B rows, 16B-aligned)
    __shared__ bf16 Bs[64 * 80];             // [64 n][64 k] pad 80
    const int tid = threadIdx.x;
    const int wid = tid >> 6, lane = tid & 63;
    const int wm = wid >> 1, wn = wid & 1;
    const int fr = lane & 15, quad = lane >> 4;
    const int m0 = by * BM, n0 = bx * 64;

    f32x4 acc[MT][2];
#pragma unroll
    for (int mt = 0; mt < MT; mt++)
#pragma unroll
        for (int nt = 0; nt < 2; nt++) acc[mt][nt] = (f32x4){0.f, 0.f, 0.f, 0.f};

    for (int k0 = 0; k0 < K; k0 += 64) {
        // ---- stage A (BM x 64) ----
        if constexpr (BM == 64) {
            const int row = tid >> 2, kg = (tid & 3) << 4;  // 16 el/thread
            if constexpr (sizeof(AT) == 2) {
                const short8* gp = (const short8*)(A + (size_t)(m0 + row) * K + k0 + kg);
                *(short8*)(&As[row * 80 + kg]) = gp[0];
                *(short8*)(&As[row * 80 + kg + 8]) = gp[1];
            } else {
                const float4* gp = (const float4*)(A + (size_t)(m0 + row) * K + k0 + kg);
#pragma unroll
                for (int j = 0; j < 4; j++) {
                    const float4 f = gp[j];
                    *(bf162*)(&As[row * 80 + kg + j * 4])     = __float22bfloat162_rn(make_float2(f.x, f.y));
                    *(bf162*)(&As[row * 80 + kg + j * 4 + 2]) = __float22bfloat162_rn(make_float2(f.z, f.w));
                }
            }
        } else {  // BM == 32
            const int row = tid >> 3, kg = (tid & 7) << 3;  // 8 el/thread
            if constexpr (sizeof(AT) == 2) {
                *(short8*)(&As[row * 80 + kg]) =
                    *(const short8*)(A + (size_t)(m0 + row) * K + k0 + kg);
            } else {
                const float4* gp = (const float4*)(A + (size_t)(m0 + row) * K + k0 + kg);
#pragma unroll
                for (int j = 0; j < 2; j++) {
                    const float4 f = gp[j];
                    *(bf162*)(&As[row * 80 + kg + j * 4])     = __float22bfloat162_rn(make_float2(f.x, f.y));
                    *(bf162*)(&As[row * 80 + kg + j * 4 + 2]) = __float22bfloat162_rn(make_float2(f.z, f.w));
                }
            }
        }
        // ---- stage B (64 n x 64 k) from BT[N][K] ----
        {
            const int row = tid >> 2, kg = (tid & 3) << 4;
            const short8* gp = (const short8*)(BT + (size_t)(n0 + row) * K + k0 + kg);
            *(short8*)(&Bs[row * 80 + kg]) = gp[0];
            *(short8*)(&Bs[row * 80 + kg + 8]) = gp[1];
        }
        __syncthreads();

        short8 af[MT][2], bf[2][2];
#pragma unroll
        for (int mt = 0; mt < MT; mt++) {
            const int arow = wm * (BM / 2) + mt * 16 + fr;
#pragma unroll
            for (int kh = 0; kh < 2; kh++)
                af[mt][kh] = *(const short8*)(&As[arow * 80 + quad * 8 + kh * 32]);
        }
#pragma unroll
        for (int nt = 0; nt < 2; nt++) {
            const int brow = wn * 32 + nt * 16 + fr;
#pragma unroll
            for (int kh = 0; kh < 2; kh++)
                bf[nt][kh] = *(const short8*)(&Bs[brow * 80 + quad * 8 + kh * 32]);
        }
#pragma unroll
        for (int kh = 0; kh < 2; kh++)
#pragma unroll
            for (int mt = 0; mt < MT; mt++)
#pragma unroll
                for (int nt = 0; nt < 2; nt++)
                    acc[mt][nt] = __builtin_amdgcn_mfma_f32_16x16x32_bf16(
                        af[mt][kh], bf[nt][kh], acc[mt][nt], 0, 0, 0);
        __syncthreads();
    }

    // ---- epilogue: C/D layout col=lane&15, row=quad*4+reg (m89-verified) ----
#pragma unroll
    for (int mt = 0; mt < MT; mt++) {
#pragma unroll
        for (int nt = 0; nt < 2; nt++) {
#pragma unroll
            for (int i = 0; i < 4; i++) {
                const int row = m0 + wm * (BM / 2) + mt * 16 + quad * 4 + i;
                const int col = n0 + wn * 32 + nt * 16 + fr;
                float v = acc[mt][nt][i];
                if (BIAS) v += bias[col];
                if (RES == 1) v += ((const float*)Res)[(size_t)row * N + col];
                if (RES == 2) v += __bfloat162float(((const bf16*)Res)[(size_t)row * N + col]);
                if (RELU) v = fmaxf(v, 0.f);
                Cout[(size_t)row * N + col] = __float2bfloat16(v);
            }
        }
    }
}

template <typename AT, int BM, bool BIAS, int RES, bool RELU>
__global__ __launch_bounds__(256) void mfma_gemm_kernel(
    const AT* __restrict__ A, const bf16* __restrict__ BT,
    const float* __restrict__ bias, const void* __restrict__ Res,
    bf16* __restrict__ Cout, int M, int N, int K)
{
    mfma_gemm_body<AT, BM, BIAS, RES, RELU>(A, BT, bias, Res, Cout, M, N, K,
                                            blockIdx.x, blockIdx.y);
}

// Fused QKV (fp32 A, z-select), grid (4, 32, 3)
__global__ __launch_bounds__(256) void qkv_kernel(
    const float* __restrict__ rowE, const float* __restrict__ colE,
    const bf16* __restrict__ WqT, const bf16* __restrict__ WkT, const bf16* __restrict__ WvT,
    bf16* __restrict__ qo, bf16* __restrict__ ko, bf16* __restrict__ vo)
{
    const int z = blockIdx.z;
    const float* A = (z == 0) ? rowE : colE;
    const bf16* BT = (z == 0) ? WqT : (z == 1) ? WkT : WvT;
    bf16* O = (z == 0) ? qo : (z == 1) ? ko : vo;
    mfma_gemm_body<float, 64, false, 0, false>(A, BT, nullptr, nullptr, O,
                                               2048, 256, 256, blockIdx.x, blockIdx.y);
}

// ================= Attention: lane=row, iterate c; k/v cvt->fp32 LDS =================
__global__ __launch_bounds__(256) void attn_kernel(
    const bf16* __restrict__ q, const bf16* __restrict__ k, const bf16* __restrict__ v,
    const float* __restrict__ cost, const float* __restrict__ m1w, const float* __restrict__ m1b,
    const float* __restrict__ m2w, const float* __restrict__ m2b,
    bf16* __restrict__ outp)
{
    __shared__ float smem[16384];  // k_lds[512][16] fp32 @0; v_lds @8192; merge scratch aliases k
    const int rt = blockIdx.x, h = blockIdx.y, b = blockIdx.z;
    const int tid = threadIdx.x, wid = tid >> 6, lane = tid & 63;

    {
        const size_t base = ((size_t)b * C_) * 256 + h * 16;
        for (int i = tid; i < 2048; i += 256) {
            const int c = i >> 2, dp = (i & 3) << 2;
            const bf162* kp = (const bf162*)(k + base + (size_t)c * 256 + dp);
            const bf162* vp = (const bf162*)(v + base + (size_t)c * 256 + dp);
            const float2 k0 = __bfloat1622float2(kp[0]), k1 = __bfloat1622float2(kp[1]);
            const float2 v0 = __bfloat1622float2(vp[0]), v1 = __bfloat1622float2(vp[1]);
            *(float4*)(&smem[c * 16 + dp]) = make_float4(k0.x, k0.y, k1.x, k1.y);
            *(float4*)(&smem[8192 + c * 16 + dp]) = make_float4(v0.x, v0.y, v1.x, v1.y);
        }
    }

    float w1a[16], w1b[16], b1v[16], w2v[16];
#pragma unroll
    for (int m = 0; m < 16; m++) {
        w1a[m] = m1w[h * 32 + m];
        w1b[m] = m1w[h * 32 + 16 + m];
        b1v[m] = m1b[h * 16 + m];
        w2v[m] = m2w[h * 16 + m];
    }
    const float b2v = m2b[h];

    const int r = rt * 64 + lane;
    float qv[16];
    {
        const bf162* qp = (const bf162*)(q + (size_t)(b * R_ + r) * 256 + h * 16);
#pragma unroll
        for (int i = 0; i < 8; i++) {
            const float2 f = __bfloat1622float2(qp[i]);
            qv[2 * i] = f.x * 0.25f; qv[2 * i + 1] = f.y * 0.25f;
        }
    }

    __syncthreads();

    const int c0 = wid * 128;
    const float* crow = cost + ((size_t)(b * R_ + r) * C_) + c0;
    float mrun = -1e30f, lrun = 0.f;
    float o[16] = {};

    for (int cc = 0; cc < 128; cc += 4) {
        const float4 cst4 = *(const float4*)(crow + cc);
#pragma unroll
        for (int u = 0; u < 4; u++) {
            const int c = c0 + cc + u;
            const float4* kr = (const float4*)(&smem[c * 16]);
            const float4 k0 = kr[0], k1 = kr[1], k2 = kr[2], k3 = kr[3];
            float d0 = fmaf(qv[0], k0.x, fmaf(qv[1], k0.y, fmaf(qv[2], k0.z, qv[3] * k0.w)));
            float d1 = fmaf(qv[4], k1.x, fmaf(qv[5], k1.y, fmaf(qv[6], k1.z, qv[7] * k1.w)));
            float d2 = fmaf(qv[8], k2.x, fmaf(qv[9], k2.y, fmaf(qv[10], k2.z, qv[11] * k2.w)));
            float d3 = fmaf(qv[12], k3.x, fmaf(qv[13], k3.y, fmaf(qv[14], k3.z, qv[15] * k3.w)));
            const float dot = (d0 + d1) + (d2 + d3);
            const float cst = (u == 0) ? cst4.x : (u == 1) ? cst4.y : (u == 2) ? cst4.z : cst4.w;
            float acc = b2v;
#pragma unroll
            for (int m = 0; m < 16; m++) {
                float t = fmaf(dot, w1a[m], fmaf(cst, w1b[m], b1v[m]));
                t = fmaxf(t, 0.f);
                acc = fmaf(t, w2v[m], acc);
            }
            const float mnew = fmaxf(mrun, acc);
            if (__any(mnew > mrun)) {
                const float alpha = __expf(mrun - mnew);
                lrun *= alpha;
#pragma unroll
                for (int d = 0; d < 16; d++) o[d] *= alpha;
                mrun = mnew;
            }
            const float p = __expf(acc - mrun);
            lrun += p;
            const float4* vr = (const float4*)(&smem[8192 + c * 16]);
            const float4 v0 = vr[0], v1 = vr[1], v2 = vr[2], v3 = vr[3];
            o[0]  = fmaf(p, v0.x, o[0]);  o[1]  = fmaf(p, v0.y, o[1]);
            o[2]  = fmaf(p, v0.z, o[2]);  o[3]  = fmaf(p, v0.w, o[3]);
            o[4]  = fmaf(p, v1.x, o[4]);  o[5]  = fmaf(p, v1.y, o[5]);
            o[6]  = fmaf(p, v1.z, o[6]);  o[7]  = fmaf(p, v1.w, o[7]);
            o[8]  = fmaf(p, v2.x, o[8]);  o[9]  = fmaf(p, v2.y, o[9]);
            o[10] = fmaf(p, v2.z, o[10]); o[11] = fmaf(p, v2.w, o[11]);
            o[12] = fmaf(p, v3.x, o[12]); o[13] = fmaf(p, v3.y, o[13]);
            o[14] = fmaf(p, v3.z, o[14]); o[15] = fmaf(p, v3.w, o[15]);
        }
    }

    __syncthreads();
    smem[wid * 64 + lane] = mrun;
    smem[256 + wid * 64 + lane] = lrun;
    {
        float* po = &smem[512 + (wid * 64 + lane) * 16];
#pragma unroll
        for (int d = 0; d < 16; d++) po[d] = o[d];
    }
    __syncthreads();

    if (tid < 64) {
        const int rr = tid;
        float mm = smem[rr];
#pragma unroll
        for (int w = 1; w < 4; w++) mm = fmaxf(mm, smem[w * 64 + rr]);
        float ll = 0.f, oo[16] = {};
#pragma unroll
        for (int w = 0; w < 4; w++) {
            const float a = __expf(smem[w * 64 + rr] - mm);
            ll = fmaf(smem[256 + w * 64 + rr], a, ll);
            const float* po = &smem[512 + (w * 64 + rr) * 16];
#pragma unroll
            for (int d = 0; d < 16; d++) oo[d] = fmaf(po[d], a, oo[d]);
        }
        const float inv = 1.f / ll;
        bf162* op = (bf162*)(outp + (size_t)(b * R_ + rt * 64 + rr) * 256 + h * 16);
#pragma unroll
        for (int j = 0; j < 8; j++)
            op[j] = __float22bfloat162_rn(make_float2(oo[2 * j] * inv, oo[2 * j + 1] * inv));
    }
}

// ================= InstanceNorm stats (bf16 input) =================
__global__ __launch_bounds__(64) void in_stats_kernel(
    const bf16* __restrict__ xin, float* __restrict__ mean, float* __restrict__ rstd)
{
    const int be = blockIdx.x;
    const int b = be >> 8, e = be & 255;
    const int lane = threadIdx.x;
    const bf16* base = xin + (size_t)b * R_ * E_ + e;
    float s = 0.f, ss = 0.f;
#pragma unroll
    for (int i = 0; i < 8; i++) {
        const float v = __bfloat162float(base[(size_t)(lane + 64 * i) * E_]);
        s += v; ss += v * v;
    }
#pragma unroll
    for (int off = 32; off; off >>= 1) {
        s += __shfl_xor(s, off, 64);
        ss += __shfl_xor(ss, off, 64);
    }
    if (lane == 0) {
        const float m = s * (1.f / 512.f);
        float var = ss * (1.f / 512.f) - m * m;
        var = fmaxf(var, 0.f);
        mean[be] = m;
        rstd[be] = rsqrtf(var + 1e-5f);
    }
}

// ================= Apply IN: bf16 in, bf16 or fp32 out =================
template <bool OUT_F32>
__global__ __launch_bounds__(256) void apply_in_kernel(
    const bf16* __restrict__ xin, const float* __restrict__ mean, const float* __restrict__ rstd,
    const float* __restrict__ g, const float* __restrict__ be, void* __restrict__ outp)
{
    const int idx = blockIdx.x * 256 + threadIdx.x;
    const int e = idx & 255;
    const int b = idx >> 17;
    const int sidx = (b << 8) | e;
    const float v = (__bfloat162float(xin[idx]) - mean[sidx]) * rstd[sidx] * g[e] + be[e];
    if (OUT_F32) ((float*)outp)[idx] = v;
    else         ((bf16*)outp)[idx] = __float2bfloat16(v);
}

extern "C" void kernel_launch(void* const* d_in, const int* in_sizes, int n_in,
                              void* d_out, int out_size, void* d_ws, size_t ws_size,
                              hipStream_t stream)
{
    (void)in_sizes; (void)n_in; (void)out_size; (void)ws_size;
    const float* row_emb = (const float*)d_in[0];
    const float* col_emb = (const float*)d_in[1];
    const float* cost    = (const float*)d_in[2];
    const float* Wq  = (const float*)d_in[3];
    const float* Wk  = (const float*)d_in[4];
    const float* Wv  = (const float*)d_in[5];
    const float* m1w = (const float*)d_in[6];
    const float* m1b = (const float*)d_in[7];
    const float* m2w = (const float*)d_in[8];
    const float* m2b = (const float*)d_in[9];
    const float* Wc  = (const float*)d_in[10];
    const float* bc  = (const float*)d_in[11];
    const float* W1  = (const float*)d_in[12];
    const float* b1  = (const float*)d_in[13];
    const float* W2  = (const float*)d_in[14];
    const float* b2  = (const float*)d_in[15];
    const float* g1  = (const float*)d_in[16];
    const float* be1 = (const float*)d_in[17];
    const float* g2  = (const float*)d_in[18];
    const float* be2 = (const float*)d_in[19];
    float* out = (float*)d_out;

    // ---- workspace layout (7.02 MB used; >=8.5 MB confirmed) ----
    char* w = (char*)d_ws;
    const size_t MB = 1u << 20;
    bf16* sq = (bf16*)(w + 0 * MB);        // q   [P1-P2]
    bf16* sk = (bf16*)(w + 1 * MB);        // k   [P1-P2]
    bf16* sv = (bf16*)(w + 2 * MB);        // v   [P1-P2]
    bf16* sa = (bf16*)(w + 3 * MB);        // attn out [P2-P3]
    bf16* sy = (bf16*)(w + 4 * MB);        // y   [P3-P4]
    bf16* sx = (bf16*)(w + 5 * MB);        // x   [P4-P5b]
    bf16* shm = (bf16*)(w + 0 * MB);       // hmid 2MB [P5] (aliases sq+sk, dead)
    bf16* st  = (bf16*)(w + 2 * MB);       // t   1MB [P5b-P6] (aliases sv, dead)
    bf16* WqT = (bf16*)(w + 6 * MB);
    bf16* WkT = (bf16*)(w + 6 * MB + 131072);
    bf16* WvT = (bf16*)(w + 6 * MB + 2 * 131072);
    bf16* WcT = (bf16*)(w + 6 * MB + 3 * 131072);
    bf16* W1T = (bf16*)(w + 6 * MB + 4 * 131072);            // 256 KB
    bf16* W2T = (bf16*)(w + 6 * MB + 4 * 131072 + 262144);   // 256 KB
    float* mean1 = (float*)(w + 7 * MB);
    float* rstd1 = mean1 + 1024;
    float* mean2 = rstd1 + 1024;
    float* rstd2 = mean2 + 1024;

    const dim3 blk(256);

    // P0: weights -> bf16 [N][K]
    transpose_cvt_kernel<<<dim3(128, 6), blk, 0, stream>>>(
        Wq, Wk, Wv, Wc, W1, W2, WqT, WkT, WvT, WcT, W1T, W2T);

    // P1: QKV (fp32 A, cvt on stage) -> bf16 q,k,v
    qkv_kernel<<<dim3(4, 32, 3), blk, 0, stream>>>(row_emb, col_emb, WqT, WkT, WvT, sq, sk, sv);

    // P2: attention -> sa bf16
    attn_kernel<<<dim3(8, 16, 4), blk, 0, stream>>>(sq, sk, sv, cost, m1w, m1b, m2w, m2b, sa);

    // P3: y = sa @ Wc + bc + row_emb -> sy bf16   (BM=32: 256 WGs)
    mfma_gemm_kernel<bf16, 32, true, 1, false><<<dim3(4, 64), blk, 0, stream>>>(
        sa, WcT, bc, (const void*)row_emb, sy, 2048, 256, 256);

    // P4: InstanceNorm1 -> sx bf16
    in_stats_kernel<<<dim3(1024), dim3(64), 0, stream>>>(sy, mean1, rstd1);
    apply_in_kernel<false><<<dim3(2048), blk, 0, stream>>>(sy, mean1, rstd1, g1, be1, sx);

    // P5a: hm = relu(x@W1+b1) -> shm bf16 [2048,512]  (256 WGs)
    mfma_gemm_kernel<bf16, 64, true, 0, true><<<dim3(8, 32), blk, 0, stream>>>(
        sx, W1T, b1, nullptr, shm, 2048, 512, 256);
    // P5b: t = hm@W2+b2+x -> st bf16  (K=512, 256 WGs)
    mfma_gemm_kernel<bf16, 32, true, 2, false><<<dim3(4, 64), blk, 0, stream>>>(
        shm, W2T, b2, (const void*)sx, st, 2048, 256, 512);

    // P6: InstanceNorm2 -> fp32 out
    in_stats_kernel<<<dim3(1024), dim3(64), 0, stream>>>(st, mean2, rstd2);
    apply_in_kernel<true><<<dim3(2048), blk, 0, stream>>>(st, mean2, rstd2, g2, be2, out);
}

// Round 6
// 187.437 us; speedup vs baseline: 3.1375x; 1.0350x over previous
//
#include <hip/hip_runtime.h>
#include <hip/hip_bf16.h>

typedef __hip_bfloat16 bf16;
typedef __hip_bfloat162 bf162;
typedef _Float16 f16;
typedef __attribute__((ext_vector_type(2))) _Float16 h2;
typedef __attribute__((ext_vector_type(8))) short short8;
typedef __attribute__((ext_vector_type(4))) float f32x4;

#define B_ 4
#define R_ 512
#define C_ 512
#define E_ 256
#define H_ 16
#define D_ 16

__device__ __forceinline__ float b2f(bf16 x) { return __bfloat162float(x); }
__device__ __forceinline__ void stout(bf16* p, float v) { *p = __float2bfloat16(v); }
__device__ __forceinline__ void stout(f16* p, float v) { *p = (f16)v; }

__device__ __forceinline__ float fdot2(h2 a, h2 b, float c) {
#if __has_builtin(__builtin_amdgcn_fdot2)
    return __builtin_amdgcn_fdot2(a, b, c, false);
#else
    return (float)a.x * (float)b.x + (float)a.y * (float)b.y + c;
#endif
}

// ================= K1: weight transpose/cvt fp32[K][N] -> bf16[N][K]; + zero stats =================
__global__ __launch_bounds__(256) void transpose_cvt_kernel(
    const float* __restrict__ Wq, const float* __restrict__ Wk, const float* __restrict__ Wv,
    const float* __restrict__ Wc, const float* __restrict__ W1, const float* __restrict__ W2,
    bf16* __restrict__ WqT, bf16* __restrict__ WkT, bf16* __restrict__ WvT,
    bf16* __restrict__ WcT, bf16* __restrict__ W1T, bf16* __restrict__ W2T,
    float* __restrict__ statsZ)
{
    __shared__ bf16 tile[32][33];
    const int wsel = blockIdx.y;
    const int tx = blockIdx.x;
    if (wsel == 0 && tx >= 64) {  // spare blocks zero the 4096 stats floats
        const int idx = (tx - 64) * 256 + threadIdx.x;
        if (idx < 4096) statsZ[idx] = 0.f;
        return;
    }
    const float* src; bf16* dst; int K, N;
    switch (wsel) {
        case 0: src = Wq; dst = WqT; K = 256; N = 256; break;
        case 1: src = Wk; dst = WkT; K = 256; N = 256; break;
        case 2: src = Wv; dst = WvT; K = 256; N = 256; break;
        case 3: src = Wc; dst = WcT; K = 256; N = 256; break;
        case 4: src = W1; dst = W1T; K = 256; N = 512; break;
        default: src = W2; dst = W2T; K = 512; N = 256; break;
    }
    const int ntiles = (K >> 5) * (N >> 5);
    if (tx >= ntiles) return;
    const int ncnt = N >> 5;
    const int tk = tx / ncnt, tn = tx % ncnt;
    const int c = threadIdx.x & 31, r = threadIdx.x >> 5;
#pragma unroll
    for (int i = 0; i < 4; i++)
        tile[r + i * 8][c] = __float2bfloat16(src[(size_t)(tk * 32 + r + i * 8) * N + tn * 32 + c]);
    __syncthreads();
#pragma unroll
    for (int i = 0; i < 4; i++)
        dst[(size_t)(tn * 32 + r + i * 8) * K + tk * 32 + c] = tile[c][r + i * 8];
}

// ================= MFMA GEMM body =================
// C[M,N] = A[M,K] @ B (BT bf16 [N][K]). BM x 64 tile, BK=64, 4 waves.
// RES: 0 none, 1 fp32, 2 bf16, 3 = instance-norm(bf16 Res) w/ stats+g+b
// NORM_A: A (bf16) normalized during staging via raw stats (sum,sumsq)
// STATS: epilogue accumulates per-(b,col) sum/sumsq into statsOut (BM=32 only)
template <typename AT, typename OT, int BM, bool BIAS, int RES, bool RELU, bool NORM_A, bool STATS>
__device__ __forceinline__ void mfma_gemm_body(
    const AT* __restrict__ A, const bf16* __restrict__ BT,
    const float* __restrict__ bias, const void* __restrict__ Res,
    const float* __restrict__ normS, const float* __restrict__ normG, const float* __restrict__ normB,
    float* __restrict__ statsOut,
    OT* __restrict__ Cout, int M, int N, int K, int bx, int by)
{
    constexpr int MT = BM / 32;
    __shared__ bf16 As[BM * 80];
    __shared__ bf16 Bs[64 * 80];
    const int tid = threadIdx.x;
    const int wid = tid >> 6, lane = tid & 63;
    const int wm = wid >> 1, wn = wid & 1;
    const int fr = lane & 15, quad = lane >> 4;
    const int m0 = by * BM, n0 = bx * 64;

    f32x4 acc[MT][2];
#pragma unroll
    for (int mt = 0; mt < MT; mt++)
#pragma unroll
        for (int nt = 0; nt < 2; nt++) acc[mt][nt] = (f32x4){0.f, 0.f, 0.f, 0.f};

    for (int k0 = 0; k0 < K; k0 += 64) {
        // ---- stage A ----
        if constexpr (BM == 64) {
            const int row = tid >> 2, kg = (tid & 3) << 4;  // 16 el/thread
            if constexpr (NORM_A) {
                const int bb = (m0 + row) >> 9;
                const bf16* ap = (const bf16*)A + (size_t)(m0 + row) * K + k0 + kg;
                bf16 tmp[16];
                *(short8*)tmp = ((const short8*)ap)[0];
                *(short8*)(tmp + 8) = ((const short8*)ap)[1];
#pragma unroll
                for (int j = 0; j < 16; j++) {
                    const int e = k0 + kg + j;
                    const float s = normS[bb * 256 + e], sq = normS[1024 + bb * 256 + e];
                    const float mn = s * (1.f / 512.f);
                    float var = sq * (1.f / 512.f) - mn * mn; var = fmaxf(var, 0.f);
                    const float x = (b2f(tmp[j]) - mn) * rsqrtf(var + 1e-5f) * normG[e] + normB[e];
                    As[row * 80 + kg + j] = __float2bfloat16(x);
                }
            } else if constexpr (sizeof(AT) == 2) {
                const short8* gp = (const short8*)((const bf16*)A + (size_t)(m0 + row) * K + k0 + kg);
                *(short8*)(&As[row * 80 + kg]) = gp[0];
                *(short8*)(&As[row * 80 + kg + 8]) = gp[1];
            } else {
                const float4* gp = (const float4*)((const float*)A + (size_t)(m0 + row) * K + k0 + kg);
#pragma unroll
                for (int j = 0; j < 4; j++) {
                    const float4 f = gp[j];
                    *(bf162*)(&As[row * 80 + kg + j * 4])     = __float22bfloat162_rn(make_float2(f.x, f.y));
                    *(bf162*)(&As[row * 80 + kg + j * 4 + 2]) = __float22bfloat162_rn(make_float2(f.z, f.w));
                }
            }
        } else {  // BM == 32
            const int row = tid >> 3, kg = (tid & 7) << 3;  // 8 el/thread
            *(short8*)(&As[row * 80 + kg]) =
                *(const short8*)((const bf16*)A + (size_t)(m0 + row) * K + k0 + kg);
        }
        // ---- stage B ----
        {
            const int row = tid >> 2, kg = (tid & 3) << 4;
            const short8* gp = (const short8*)(BT + (size_t)(n0 + row) * K + k0 + kg);
            *(short8*)(&Bs[row * 80 + kg]) = gp[0];
            *(short8*)(&Bs[row * 80 + kg + 8]) = gp[1];
        }
        __syncthreads();

        short8 af[MT][2], bfr[2][2];
#pragma unroll
        for (int mt = 0; mt < MT; mt++) {
            const int arow = wm * (BM / 2) + mt * 16 + fr;
#pragma unroll
            for (int kh = 0; kh < 2; kh++)
                af[mt][kh] = *(const short8*)(&As[arow * 80 + quad * 8 + kh * 32]);
        }
#pragma unroll
        for (int nt = 0; nt < 2; nt++) {
            const int brow = wn * 32 + nt * 16 + fr;
#pragma unroll
            for (int kh = 0; kh < 2; kh++)
                bfr[nt][kh] = *(const short8*)(&Bs[brow * 80 + quad * 8 + kh * 32]);
        }
#pragma unroll
        for (int kh = 0; kh < 2; kh++)
#pragma unroll
            for (int mt = 0; mt < MT; mt++)
#pragma unroll
                for (int nt = 0; nt < 2; nt++)
                    acc[mt][nt] = __builtin_amdgcn_mfma_f32_16x16x32_bf16(
                        af[mt][kh], bfr[nt][kh], acc[mt][nt], 0, 0, 0);
        __syncthreads();
    }

    // ---- epilogue (C/D: col=lane&15, row=quad*4+reg) ----
    float vsum[2] = {0.f, 0.f}, vss[2] = {0.f, 0.f};
#pragma unroll
    for (int mt = 0; mt < MT; mt++) {
#pragma unroll
        for (int nt = 0; nt < 2; nt++) {
#pragma unroll
            for (int i = 0; i < 4; i++) {
                const int row = m0 + wm * (BM / 2) + mt * 16 + quad * 4 + i;
                const int col = n0 + wn * 32 + nt * 16 + fr;
                float v = acc[mt][nt][i];
                if (BIAS) v += bias[col];
                if constexpr (RES == 1) v += ((const float*)Res)[(size_t)row * N + col];
                if constexpr (RES == 2) v += b2f(((const bf16*)Res)[(size_t)row * N + col]);
                if constexpr (RES == 3) {
                    const int bb = row >> 9;
                    const float yv = b2f(((const bf16*)Res)[(size_t)row * N + col]);
                    const float s = normS[bb * 256 + col], sq = normS[1024 + bb * 256 + col];
                    const float mn = s * (1.f / 512.f);
                    float var = sq * (1.f / 512.f) - mn * mn; var = fmaxf(var, 0.f);
                    v += (yv - mn) * rsqrtf(var + 1e-5f) * normG[col] + normB[col];
                }
                if (RELU) v = fmaxf(v, 0.f);
                stout(&Cout[(size_t)row * N + col], v);
                if (STATS) { vsum[nt] += v; vss[nt] += v * v; }
            }
        }
    }
    if constexpr (STATS) {  // BM==32: tile rows all in one b
        __syncthreads();
        float* sred = (float*)As;  // 256 floats, alias dead A-tile
#pragma unroll
        for (int nt = 0; nt < 2; nt++) {
            float a = vsum[nt]; a += __shfl_xor(a, 16, 64); a += __shfl_xor(a, 32, 64);
            float c = vss[nt];  c += __shfl_xor(c, 16, 64); c += __shfl_xor(c, 32, 64);
            if (quad == 0) {
                const int col = wn * 32 + nt * 16 + fr;
                sred[wm * 128 + col * 2 + 0] = a;
                sred[wm * 128 + col * 2 + 1] = c;
            }
        }
        __syncthreads();
        if (tid < 128) {
            const int col = tid >> 1, w = tid & 1;
            const float tot = sred[col * 2 + w] + sred[128 + col * 2 + w];
            atomicAdd(&statsOut[w * 1024 + (m0 >> 9) * 256 + n0 + col], tot);
        }
    }
}

template <typename AT, typename OT, int BM, bool BIAS, int RES, bool RELU, bool NORM_A, bool STATS>
__global__ __launch_bounds__(256) void mfma_gemm_kernel(
    const AT* __restrict__ A, const bf16* __restrict__ BT,
    const float* __restrict__ bias, const void* __restrict__ Res,
    const float* __restrict__ normS, const float* __restrict__ normG, const float* __restrict__ normB,
    float* __restrict__ statsOut, OT* __restrict__ Cout, int M, int N, int K)
{
    mfma_gemm_body<AT, OT, BM, BIAS, RES, RELU, NORM_A, STATS>(
        A, BT, bias, Res, normS, normG, normB, statsOut, Cout, M, N, K, blockIdx.x, blockIdx.y);
}

// ================= K2: fused QKV -> f16 =================
__global__ __launch_bounds__(256) void qkv_kernel(
    const float* __restrict__ rowE, const float* __restrict__ colE,
    const bf16* __restrict__ WqT, const bf16* __restrict__ WkT, const bf16* __restrict__ WvT,
    f16* __restrict__ qo, f16* __restrict__ ko, f16* __restrict__ vo)
{
    const int z = blockIdx.z;
    const float* A = (z == 0) ? rowE : colE;
    const bf16* BT = (z == 0) ? WqT : (z == 1) ? WkT : WvT;
    f16* O = (z == 0) ? qo : (z == 1) ? ko : vo;
    mfma_gemm_body<float, f16, 64, false, 0, false, false, false>(
        A, BT, nullptr, nullptr, nullptr, nullptr, nullptr, nullptr, O,
        2048, 256, 256, blockIdx.x, blockIdx.y);
}

// ================= K3: attention partial; grid (rt8 x cs2, h16, b4) =================
// WG: 64 rows (lane=row), 256 columns [cs*256, cs*256+256); 4 waves x 64 c.
// k f16 LDS (broadcast, fdot2), v f32 LDS. Writes unnormalized (m, l, o-bf16).
__global__ __launch_bounds__(256) void attn_partial_kernel(
    const f16* __restrict__ q, const f16* __restrict__ k, const f16* __restrict__ v,
    const float* __restrict__ cost, const float* __restrict__ m1w, const float* __restrict__ m1b,
    const float* __restrict__ m2w, const float* __restrict__ m2b,
    float* __restrict__ pm, float* __restrict__ pl, bf16* __restrict__ po)
{
    __shared__ char slds[24576];          // k f16 [256][16] @0 (8KB) | v f32 [256][16] @8192 (16KB)
    f16* kbuf = (f16*)slds;
    float* vbuf = (float*)(slds + 8192);
    float* sm = (float*)slds;             // merge alias (4608 floats), after final barrier

    const int rt = blockIdx.x >> 1, cs = blockIdx.x & 1;
    const int h = blockIdx.y, b = blockIdx.z;
    const int tid = threadIdx.x, wid = tid >> 6, lane = tid & 63;

    // ---- stage k (f16) and v (f16->f32) for this (b,h,cs) ----
    {
        const size_t base = ((size_t)b * C_) * 256 + h * 16 + (size_t)cs * 256 * 256;
        for (int i = tid; i < 512; i += 256) {
            const int lc = i >> 1, dp = (i & 1) * 8;
            const size_t g = base + (size_t)lc * 256 + dp;
            *(short8*)(&kbuf[lc * 16 + dp]) = *(const short8*)(k + g);
            const h2* vp = (const h2*)(v + g);
#pragma unroll
            for (int j = 0; j < 4; j++) {
                const h2 t = vp[j];
                vbuf[lc * 16 + dp + 2 * j]     = (float)t.x;
                vbuf[lc * 16 + dp + 2 * j + 1] = (float)t.y;
            }
        }
    }

    // per-head MLP weights
    h2 w1ab[16]; float b1v[16], w2v[16];
#pragma unroll
    for (int m = 0; m < 16; m++) {
        h2 w; w.x = (f16)m1w[h * 32 + m]; w.y = (f16)m1w[h * 32 + 16 + m];
        w1ab[m] = w;
        b1v[m] = m1b[h * 16 + m];
        w2v[m] = m2w[h * 16 + m];
    }
    const float b2v = m2b[h];

    // this lane's q row (f16 pairs)
    const int r = rt * 64 + lane;
    h2 qh[8];
    {
        const h2* qp = (const h2*)(q + (size_t)(b * R_ + r) * 256 + h * 16);
#pragma unroll
        for (int i = 0; i < 8; i++) qh[i] = qp[i];
    }

    __syncthreads();

    const float* crow = cost + (size_t)(b * R_ + r) * C_ + cs * 256 + wid * 64;
    float mrun = -1e30f, lrun = 0.f;
    float o[16] = {};

    for (int cc = 0; cc < 64; cc += 4) {
        const float4 cst4 = *(const float4*)(crow + cc);
#pragma unroll
        for (int u = 0; u < 4; u++) {
            const int lc = wid * 64 + cc + u;
            const h2* kr = (const h2*)(&kbuf[lc * 16]);
            float d = 0.f;
#pragma unroll
            for (int i = 0; i < 8; i++) d = fdot2(qh[i], kr[i], d);
            const float dot = d * 0.25f;
            const float cst = (u == 0) ? cst4.x : (u == 1) ? cst4.y : (u == 2) ? cst4.z : cst4.w;
            h2 dc; dc.x = (f16)dot; dc.y = (f16)cst;
            float acc = b2v;
#pragma unroll
            for (int m = 0; m < 16; m++) {
                float t = fdot2(dc, w1ab[m], b1v[m]);
                t = fmaxf(t, 0.f);
                acc = fmaf(t, w2v[m], acc);
            }
            const float mnew = fmaxf(mrun, acc);
            if (__any(mnew > mrun)) {
                const float alpha = __expf(mrun - mnew);
                lrun *= alpha;
#pragma unroll
                for (int d2 = 0; d2 < 16; d2++) o[d2] *= alpha;
                mrun = mnew;
            }
            const float p = __expf(acc - mrun);
            lrun += p;
            const float4* vr = (const float4*)(&vbuf[lc * 16]);
            const float4 v0 = vr[0], v1 = vr[1], v2 = vr[2], v3 = vr[3];
            o[0]  = fmaf(p, v0.x, o[0]);  o[1]  = fmaf(p, v0.y, o[1]);
            o[2]  = fmaf(p, v0.z, o[2]);  o[3]  = fmaf(p, v0.w, o[3]);
            o[4]  = fmaf(p, v1.x, o[4]);  o[5]  = fmaf(p, v1.y, o[5]);
            o[6]  = fmaf(p, v1.z, o[6]);  o[7]  = fmaf(p, v1.w, o[7]);
            o[8]  = fmaf(p, v2.x, o[8]);  o[9]  = fmaf(p, v2.y, o[9]);
            o[10] = fmaf(p, v2.z, o[10]); o[11] = fmaf(p, v2.w, o[11]);
            o[12] = fmaf(p, v3.x, o[12]); o[13] = fmaf(p, v3.y, o[13]);
            o[14] = fmaf(p, v3.z, o[14]); o[15] = fmaf(p, v3.w, o[15]);
        }
    }

    // ---- intra-WG merge of 4 wave partials -> one (m,l,o) per row ----
    __syncthreads();
    sm[wid * 64 + lane] = mrun;
    sm[256 + wid * 64 + lane] = lrun;
    {
        float* p = &sm[512 + (wid * 64 + lane) * 16];
#pragma unroll
        for (int d = 0; d < 16; d++) p[d] = o[d];
    }
    __syncthreads();

    if (tid < 64) {
        const int rr = tid;
        float mm = sm[rr];
#pragma unroll
        for (int w = 1; w < 4; w++) mm = fmaxf(mm, sm[w * 64 + rr]);
        float ll = 0.f, oo[16] = {};
#pragma unroll
        for (int w = 0; w < 4; w++) {
            const float a = __expf(sm[w * 64 + rr] - mm);
            ll = fmaf(sm[256 + w * 64 + rr], a, ll);
            const float* p = &sm[512 + (w * 64 + rr) * 16];
#pragma unroll
            for (int d = 0; d < 16; d++) oo[d] = fmaf(p[d], a, oo[d]);
        }
        const int idx = (b * H_ + h) * R_ + rt * 64 + rr;
        pm[cs * 32768 + idx] = mm;
        pl[cs * 32768 + idx] = ll;
        bf162* pp = (bf162*)(po + (size_t)(cs * 32768 + idx) * 16);
#pragma unroll
        for (int j = 0; j < 8; j++)
            pp[j] = __float22bfloat162_rn(make_float2(oo[2 * j], oo[2 * j + 1]));
    }
}

// ================= K4: merge the 2 c-split partials -> sa bf16 =================
__global__ __launch_bounds__(256) void attn_merge_kernel(
    const float* __restrict__ pm, const float* __restrict__ pl, const bf16* __restrict__ po,
    bf16* __restrict__ sa)
{
    const int idx = blockIdx.x * 256 + threadIdx.x;  // 32768
    const float m0 = pm[idx], m1 = pm[32768 + idx];
    const float mm = fmaxf(m0, m1);
    const float a0 = __expf(m0 - mm), a1 = __expf(m1 - mm);
    const float l = pl[idx] * a0 + pl[32768 + idx] * a1;
    const float inv = 1.f / l;
    const bf162* p0 = (const bf162*)(po + (size_t)idx * 16);
    const bf162* p1 = (const bf162*)(po + (size_t)(32768 + idx) * 16);
    const int b = idx >> 13, h = (idx >> 9) & 15, r = idx & 511;
    bf162* op = (bf162*)(sa + (size_t)(b * R_ + r) * 256 + h * 16);
#pragma unroll
    for (int j = 0; j < 8; j++) {
        const float2 f0 = __bfloat1622float2(p0[j]);
        const float2 f1 = __bfloat1622float2(p1[j]);
        op[j] = __float22bfloat162_rn(make_float2(
            (f0.x * a0 + f1.x * a1) * inv, (f0.y * a0 + f1.y * a1) * inv));
    }
}

// ================= K8: final instance-norm from raw stats -> fp32 out =================
__global__ __launch_bounds__(256) void apply_in2_kernel(
    const bf16* __restrict__ xin, const float* __restrict__ stats,
    const float* __restrict__ g, const float* __restrict__ be, float* __restrict__ outp)
{
    const int base = (blockIdx.x * 256 + threadIdx.x) * 4;  // < 524288
    const int b = base >> 17;
    const bf162* xp = (const bf162*)(xin + base);
    const float2 x0 = __bfloat1622float2(xp[0]), x1 = __bfloat1622float2(xp[1]);
    const float xv[4] = {x0.x, x0.y, x1.x, x1.y};
    float4 r;
    float* rp = (float*)&r;
#pragma unroll
    for (int j = 0; j < 4; j++) {
        const int e = (base & 255) + j;
        const float s = stats[b * 256 + e], sq = stats[1024 + b * 256 + e];
        const float mn = s * (1.f / 512.f);
        float var = sq * (1.f / 512.f) - mn * mn; var = fmaxf(var, 0.f);
        rp[j] = (xv[j] - mn) * rsqrtf(var + 1e-5f) * g[e] + be[e];
    }
    *(float4*)(outp + base) = r;
}

extern "C" void kernel_launch(void* const* d_in, const int* in_sizes, int n_in,
                              void* d_out, int out_size, void* d_ws, size_t ws_size,
                              hipStream_t stream)
{
    (void)in_sizes; (void)n_in; (void)out_size; (void)ws_size;
    const float* row_emb = (const float*)d_in[0];
    const float* col_emb = (const float*)d_in[1];
    const float* cost    = (const float*)d_in[2];
    const float* Wq  = (const float*)d_in[3];
    const float* Wk  = (const float*)d_in[4];
    const float* Wv  = (const float*)d_in[5];
    const float* m1w = (const float*)d_in[6];
    const float* m1b = (const float*)d_in[7];
    const float* m2w = (const float*)d_in[8];
    const float* m2b = (const float*)d_in[9];
    const float* Wc  = (const float*)d_in[10];
    const float* bc  = (const float*)d_in[11];
    const float* W1  = (const float*)d_in[12];
    const float* b1  = (const float*)d_in[13];
    const float* W2  = (const float*)d_in[14];
    const float* b2  = (const float*)d_in[15];
    const float* g1  = (const float*)d_in[16];
    const float* be1 = (const float*)d_in[17];
    const float* g2  = (const float*)d_in[18];
    const float* be2 = (const float*)d_in[19];
    float* out = (float*)d_out;

    // ---- workspace layout (peak use ~7.9 MB; ws >= 8.5 MB verified by probe) ----
    char* w = (char*)d_ws;
    const size_t MB = 1u << 20;
    f16*  sq  = (f16*)(w + 0 * MB);          // [K2..K3]
    f16*  sk  = (f16*)(w + 1 * MB);          // [K2..K3]
    f16*  sv  = (f16*)(w + 2 * MB);          // [K2..K3]
    bf16* sa  = (bf16*)(w + 3 * MB);         // [K4..K5]
    bf16* po  = (bf16*)(w + 4 * MB);         // 2 MB [K3..K4]
    bf16* sy  = (bf16*)(w + 4 * MB);         // 1 MB [K5..K7] (po dead)
    bf16* shm = (bf16*)(w + 0 * MB);         // 2 MB [K6..K7] (sq/sk dead)
    bf16* st  = (bf16*)(w + 2 * MB);         // 1 MB [K7..K8] (sv dead)
    bf16* WqT = (bf16*)(w + 6 * MB);
    bf16* WkT = (bf16*)(w + 6 * MB + 131072);
    bf16* WvT = (bf16*)(w + 6 * MB + 2 * 131072);
    bf16* WcT = (bf16*)(w + 6 * MB + 3 * 131072);
    bf16* W1T = (bf16*)(w + 6 * MB + 4 * 131072);
    bf16* W2T = (bf16*)(w + 6 * MB + 4 * 131072 + 262144);
    float* stats1 = (float*)(w + 7 * MB);            // 2048 f32 (sum | sumsq)
    float* stats2 = stats1 + 2048;                   // 2048 f32
    float* pm = (float*)(w + 7 * MB + 16384);        // 2*32768 f32
    float* pl = pm + 2 * 32768;

    const dim3 blk(256);

    // K1: weight transpose/cvt + zero stats
    transpose_cvt_kernel<<<dim3(128, 6), blk, 0, stream>>>(
        Wq, Wk, Wv, Wc, W1, W2, WqT, WkT, WvT, WcT, W1T, W2T, stats1);

    // K2: QKV -> f16
    qkv_kernel<<<dim3(4, 32, 3), blk, 0, stream>>>(row_emb, col_emb, WqT, WkT, WvT, sq, sk, sv);

    // K3: attention partials (1024 WGs)
    attn_partial_kernel<<<dim3(16, 16, 4), blk, 0, stream>>>(
        sq, sk, sv, cost, m1w, m1b, m2w, m2b, pm, pl, po);

    // K4: merge -> sa
    attn_merge_kernel<<<dim3(128), blk, 0, stream>>>(pm, pl, po, sa);

    // K5: y = sa @ Wc + bc + row_emb -> sy (+ stats1)
    mfma_gemm_kernel<bf16, bf16, 32, true, 1, false, false, true><<<dim3(4, 64), blk, 0, stream>>>(
        sa, WcT, bc, (const void*)row_emb, nullptr, nullptr, nullptr, stats1, sy, 2048, 256, 256);

    // K6: hm = relu(norm1(sy) @ W1 + b1) -> shm  (IN1 applied in A-staging)
    mfma_gemm_kernel<bf16, bf16, 64, true, 0, true, true, false><<<dim3(8, 32), blk, 0, stream>>>(
        sy, W1T, b1, nullptr, stats1, g1, be1, nullptr, shm, 2048, 512, 256);

    // K7: t = hm @ W2 + b2 + norm1(sy) -> st (+ stats2)
    mfma_gemm_kernel<bf16, bf16, 32, true, 3, false, false, true><<<dim3(4, 64), blk, 0, stream>>>(
        shm, W2T, b2, (const void*)sy, stats1, g1, be1, stats2, st, 2048, 256, 512);

    // K8: out = norm2(st)
    apply_in2_kernel<<<dim3(512), blk, 0, stream>>>(st, stats2, g2, be2, out);
}